// Round 2
// baseline (250.373 us; speedup 1.0000x reference)
//
#include <hip/hip_runtime.h>

// DynamicUpsamplingFilter: out[b,c,h,w] = sum_{dy,dx} f[b,3*dy+dx,h,w] * x[b,c,h+dy-1,w+dx-1]
// x: [4,128,180,320] f32, filters: [4,9,180,320] f32, out: [4,128,180,320] f32.
//
// R5: MLP fix. R3/R4 were latency-bound at 33% HBM: the 18-float4 per-thread
// filter cache (72 VGPRs) never fit the compiler's 64-VGPR choice (spill or
// per-channel reload), so waves averaged <1 pending load (Little's law from
// 2.65 TB/s @ ~900cy says ~300 B/wave in flight). Restructure:
//   - Cross-thread filter sharing via LDS: block = 16 channels x 16 w4 for
//     one (b, h-pair, w-span). 18x16 float4 = 4.6 KB staged once; each
//     thread ds_reads each filter f4 exactly once at its FMA.
//   - One channel per thread: every loaded value is single-use -> live set
//     ~50 VGPRs, nothing to spill; 14400 blocks -> ~32 resident waves/CU,
//     TLP alone covers HBM latency.
//   - XCD-aware decode: 8 cgrp siblings of a tile consecutive on one XCD
//     (filter tile fetched once per XCD); each XCD owns a contiguous h-band
//     (x halo rows L2-hit).

#define CC 128
#define HH 180
#define W4 80          // float4s per image row
#define NF 9
#define H2 90          // h-pairs
#define CLPB 16        // channels per block
#define WLPB 16        // w4 per block
#define WS 5           // w-spans (80/16)
#define CGRPS (CC / CLPB)  // 8
#define NXCD 8
#define TILES (4 * H2 * WS)        // 1800 (b,h2,ws) tiles
#define TPX (TILES / NXCD)         // 225 tiles per XCD
#define NBLK (TILES * CGRPS)       // 14400 blocks

__device__ __forceinline__ void fma_row(float4& acc, const float4 f0, const float4 f1,
                                        const float4 f2, const float aL, const float4 B,
                                        const float cR) {
    acc.x = fmaf(f0.x, aL,  fmaf(f1.x, B.x, fmaf(f2.x, B.y, acc.x)));
    acc.y = fmaf(f0.y, B.x, fmaf(f1.y, B.y, fmaf(f2.y, B.z, acc.y)));
    acc.z = fmaf(f0.z, B.y, fmaf(f1.z, B.z, fmaf(f2.z, B.w, acc.z)));
    acc.w = fmaf(f0.w, B.z, fmaf(f1.w, B.w, fmaf(f2.w, cR,  acc.w)));
}

__global__ __launch_bounds__(256) void duf_kernel(
    const float* __restrict__ x,
    const float* __restrict__ f,
    float* __restrict__ out)
{
    // ---- XCD-aware block decode (consecutive blockIdx round-robin over 8 XCDs)
    int raw = blockIdx.x;
    int xcd = raw & 7;
    int li  = raw >> 3;            // 0..NBLK/8-1, sequential on this XCD
    int cgrp = li & 7;             // 8 cgrp siblings back-to-back on one XCD
    int tl   = li >> 3;            // 0..TPX-1
    int tile = xcd * TPX + tl;     // contiguous h-band per XCD
    int b   = tile / (H2 * WS);
    int rem = tile % (H2 * WS);
    int h2  = rem / WS;
    int ws  = rem % WS;
    int h   = h2 * 2;

    int tid = threadIdx.x;
    int wl  = tid & 15;            // w4 within span
    int cl  = tid >> 4;            // channel within block
    int c   = cgrp * CLPB + cl;
    int gw4 = ws * WLPB + wl;      // global float4 column

    const float4* f4 = (const float4*)f;
    float4* o4 = (float4*)out;

    // ---- stage filter tile: fl[(i*2+row)*16 + wl], i=tap 0..8, row=0/1
    __shared__ float4 fl[NF * 2 * WLPB];   // 288 float4 = 4608 B
    for (int s = tid; s < NF * 2 * WLPB; s += 256) {
        int swl = s & 15;
        int sr  = (s >> 4) & 1;
        int si  = s >> 5;
        fl[s] = f4[((size_t)(b * NF + si) * HH + h + sr) * W4 + ws * WLPB + swl];
    }
    __syncthreads();

    // ---- compute: one channel, one h-pair, one float4 column per thread
    const size_t xcbase = (size_t)(b * CC + c) * HH * W4;  // float4 units
    float4 a0 = make_float4(0.f, 0.f, 0.f, 0.f);
    float4 a1 = make_float4(0.f, 0.f, 0.f, 0.f);
#pragma unroll
    for (int r = 0; r < 4; ++r) {          // x rows h-1 .. h+2
        int hr = h - 1 + r;
        float4 B = make_float4(0.f, 0.f, 0.f, 0.f);
        float aL = 0.f, cR = 0.f;
        if (hr >= 0 && hr < HH) {          // block-uniform branch
            const float* xr = x + (xcbase + (size_t)hr * W4) * 4;
            B = *(const float4*)(xr + gw4 * 4);
            if (gw4 > 0)      aL = xr[gw4 * 4 - 1];   // exec-masked
            if (gw4 < W4 - 1) cR = xr[gw4 * 4 + 4];   // exec-masked
        }
        if (r < 3) {                       // taps for output row h
            float4 f0 = fl[((3 * r + 0) * 2 + 0) * 16 + wl];
            float4 f1 = fl[((3 * r + 1) * 2 + 0) * 16 + wl];
            float4 f2 = fl[((3 * r + 2) * 2 + 0) * 16 + wl];
            fma_row(a0, f0, f1, f2, aL, B, cR);
        }
        if (r > 0) {                       // taps for output row h+1
            float4 g0 = fl[((3 * r - 3) * 2 + 1) * 16 + wl];
            float4 g1 = fl[((3 * r - 2) * 2 + 1) * 16 + wl];
            float4 g2 = fl[((3 * r - 1) * 2 + 1) * 16 + wl];
            fma_row(a1, g0, g1, g2, aL, B, cR);
        }
    }

    size_t ob = ((size_t)(b * CC + c) * HH + h) * W4 + gw4;
    o4[ob]      = a0;
    o4[ob + W4] = a1;
}

extern "C" void kernel_launch(void* const* d_in, const int* in_sizes, int n_in,
                              void* d_out, int out_size, void* d_ws, size_t ws_size,
                              hipStream_t stream) {
    const float* x = (const float*)d_in[0];
    const float* f = (const float*)d_in[1];
    float* out = (float*)d_out;
    duf_kernel<<<NBLK, 256, 0, stream>>>(x, f, out);
}

// Round 3
// 231.934 us; speedup vs baseline: 1.0795x; 1.0795x over previous
//
#include <hip/hip_runtime.h>

// DynamicUpsamplingFilter: out[b,c,h,w] = sum_{dy,dx} f[b,3*dy+dx,h,w] * x[b,c,h+dy-1,w+dx-1]
// x: [4,128,180,320] f32, filters: [4,9,180,320] f32, out: [4,128,180,320] f32.
//
// R6: latency-serialization fix. R3/R5 ran at ~100us with all pipes idle:
// per-wave loads were emitted as load->waitcnt->use chains (conditional
// branches around row loads, halo clauses, 64-VGPR pressure), so each wave
// had <1 load in flight (Little's law from 2.6 TB/s @ ~900cy). Changes:
//   - Branch-free batched loads: clamped row/col addressing, all 12 x values
//     (4 rows x {float4 B, scalar aL, scalar cR}) loaded into named regs in
//     one clause, THEN zero-fixups via cndmask. One vmcnt wait, not twelve.
//   - Staging overlap: filter loads -> x loads -> ds_write -> barrier, so
//     x-load latency hides under the staging wait.
//   - __launch_bounds__(256,6): 85-VGPR cap -> 24 resident waves/CU over
//     56 blocks/CU of work; MLP x TLP >> 9.2 KB/CU needed for full HBM BW.
//   - Keeps R5's LDS filter sharing (4.6 KB/block) + XCD h-banding.

#define CC 128
#define HH 180
#define WW 320
#define W4 80          // float4s per image row
#define NF 9
#define H2 90          // h-pairs
#define WLPB 16        // w4 per block
#define WS 5           // w-spans (80/16)
#define TILES (4 * H2 * WS)   // 1800 (b,h2,ws) tiles
#define TPX (TILES / 8)       // 225 tiles per XCD
#define NBLK (TILES * 8)      // 14400 blocks (x8 channel-groups)

__device__ __forceinline__ void fma_row(float4& acc, const float4 f0, const float4 f1,
                                        const float4 f2, const float aL, const float4 B,
                                        const float cR) {
    acc.x = fmaf(f0.x, aL,  fmaf(f1.x, B.x, fmaf(f2.x, B.y, acc.x)));
    acc.y = fmaf(f0.y, B.x, fmaf(f1.y, B.y, fmaf(f2.y, B.z, acc.y)));
    acc.z = fmaf(f0.z, B.y, fmaf(f1.z, B.z, fmaf(f2.z, B.w, acc.z)));
    acc.w = fmaf(f0.w, B.z, fmaf(f1.w, B.w, fmaf(f2.w, cR,  acc.w)));
}

__global__ __launch_bounds__(256, 6) void duf_kernel(
    const float* __restrict__ x,
    const float* __restrict__ f,
    float* __restrict__ out)
{
    // ---- XCD-aware decode: 8 cgrp siblings consecutive on one XCD,
    // each XCD owns a contiguous h-band (x halo rows + filter tile L2-hit).
    int raw = blockIdx.x;
    int xcd = raw & 7;
    int li  = raw >> 3;
    int cgrp = li & 7;
    int tl   = li >> 3;                 // 0..TPX-1
    int tile = xcd * TPX + tl;
    int b   = tile / (H2 * WS);
    int rem = tile - b * (H2 * WS);
    int h2  = rem / WS;
    int ws  = rem - h2 * WS;
    int h   = h2 * 2;

    int tid = threadIdx.x;
    int wl  = tid & 15;                 // w4 within span
    int cl  = tid >> 4;                 // channel within block
    int c   = cgrp * 16 + cl;
    int gw4 = ws * WLPB + wl;           // global float4 column

    const float4* f4 = (const float4*)f;
    float4* o4 = (float4*)out;

    __shared__ float4 fl[NF * 2 * WLPB];   // 288 float4 = 4608 B

    // ---- issue filter staging loads (to regs; LDS write deferred)
    const size_t ftile = ((size_t)(b * NF) * HH + h) * W4 + ws * WLPB;
    int s0 = tid;                          // s = (tap*2 + row)*16 + swl
    float4 st0 = f4[ftile + (size_t)(s0 >> 5) * (HH * W4) + ((s0 >> 4) & 1) * W4 + (s0 & 15)];
    const bool has1 = (tid < 32);
    int s1 = 256 + tid;
    float4 st1 = make_float4(0.f, 0.f, 0.f, 0.f);
    if (has1)
        st1 = f4[ftile + (size_t)(s1 >> 5) * (HH * W4) + ((s1 >> 4) & 1) * W4 + (s1 & 15)];

    // ---- issue ALL x loads: 4 rows x {B float4, aL scalar, cR scalar},
    // clamped addresses, no branches. Fixups come after.
    const float* xc = x + (size_t)(b * CC + c) * HH * WW;
    const int wB = gw4 * 4;
    const int wA = (gw4 == 0)      ? 0      : wB - 1;
    const int wC = (gw4 == W4 - 1) ? WW - 1 : wB + 4;

    float4 B_[4];
    float  aL_[4], cR_[4];
#pragma unroll
    for (int r = 0; r < 4; ++r) {
        int hr  = h - 1 + r;
        int hrc = min(max(hr, 0), HH - 1);          // v_med3
        const float* xr = xc + (size_t)hrc * WW;
        B_[r]  = *(const float4*)(xr + wB);
        aL_[r] = xr[wA];
        cR_[r] = xr[wC];
    }

    // ---- complete staging, then barrier (x loads remain in flight past here)
    fl[s0] = st0;
    if (has1) fl[s1] = st1;
    __syncthreads();

    // ---- zero-fixups (block-uniform row validity; lane-edge columns)
    const float4 z4 = make_float4(0.f, 0.f, 0.f, 0.f);
    if (h == 0)      { B_[0] = z4; aL_[0] = 0.f; cR_[0] = 0.f; }
    if (h == HH - 2) { B_[3] = z4; aL_[3] = 0.f; cR_[3] = 0.f; }
    if (gw4 == 0)      { aL_[0] = aL_[1] = aL_[2] = aL_[3] = 0.f; }
    if (gw4 == W4 - 1) { cR_[0] = cR_[1] = cR_[2] = cR_[3] = 0.f; }

    // ---- FMAs: taps from LDS (each read once, broadcast across channels)
    float4 a0 = z4, a1 = z4;
#pragma unroll
    for (int r = 0; r < 4; ++r) {
        if (r < 3) {
            float4 t0 = fl[((3 * r + 0) * 2 + 0) * 16 + wl];
            float4 t1 = fl[((3 * r + 1) * 2 + 0) * 16 + wl];
            float4 t2 = fl[((3 * r + 2) * 2 + 0) * 16 + wl];
            fma_row(a0, t0, t1, t2, aL_[r], B_[r], cR_[r]);
        }
        if (r > 0) {
            float4 g0 = fl[((3 * r - 3) * 2 + 1) * 16 + wl];
            float4 g1 = fl[((3 * r - 2) * 2 + 1) * 16 + wl];
            float4 g2 = fl[((3 * r - 1) * 2 + 1) * 16 + wl];
            fma_row(a1, g0, g1, g2, aL_[r], B_[r], cR_[r]);
        }
    }

    size_t ob = ((size_t)(b * CC + c) * HH + h) * W4 + gw4;
    o4[ob]      = a0;
    o4[ob + W4] = a1;
}

extern "C" void kernel_launch(void* const* d_in, const int* in_sizes, int n_in,
                              void* d_out, int out_size, void* d_ws, size_t ws_size,
                              hipStream_t stream) {
    const float* x = (const float*)d_in[0];
    const float* f = (const float*)d_in[1];
    float* out = (float*)d_out;
    duf_kernel<<<NBLK, 256, 0, stream>>>(x, f, out);
}